// Round 5
// baseline (523.719 us; speedup 1.0000x reference)
//
#include <hip/hip_runtime.h>

typedef _Float16 f16x8 __attribute__((ext_vector_type(8)));
typedef float f32x4 __attribute__((ext_vector_type(4)));

#define BN   65536   // B*N = 16*4096
#define MSZ  4096
#define TOPK 8

#define MFMA(a, b, c) __builtin_amdgcn_mfma_f32_16x16x32_f16(a, b, c, 0, 0, 0)

// XOR-swizzled byte offset in an [R rows][512 B] LDS region. Mixes row bit 3
// so rows r and r+8 (the two l16-aliases of one ds_read_b128) land on
// different bank groups. Works for 32- and 64-row regions.
__device__ __forceinline__ int swz2(int r, int cb) {
    return (r << 9) + (cb ^ ((((r >> 3) ^ r) & 7) << 4));
}

// ---------------------------------------------------------------------------
// Single prep kernel:
//  - keys -> f16 PRE-SWIZZLED 16 KB tile image (128 tiles x 32 keys), so a
//    linear global_load_lds fill reproduces the swizzled LDS layout.
//  - Wq/W1/W2 -> MFMA-fragment-ordered f16 (lane-contiguous 1 KB wave loads):
//    element W[k][n] at ((n>>4)*KF + k>>5)*512 + (((k>>3)&3)*16 + (n&15))*8 + (k&7)
// ---------------------------------------------------------------------------
__global__ void prep(const float* __restrict__ keys, _Float16* __restrict__ keysSW,
                     const float* __restrict__ Wq, _Float16* __restrict__ Wq2,
                     const float* __restrict__ W1, _Float16* __restrict__ W12,
                     const float* __restrict__ W2, _Float16* __restrict__ W22) {
    const int b = blockIdx.x, tid = threadIdx.x;
    if (b < 512) {                      // keys: 4096 x 256 -> 128 tiles x 16 KB
        int g = b * 256 + tid;          // f16x8 units: [0, 131072)
        int k = g >> 5, f8 = g & 31;
        float4 x = *(const float4*)(keys + (size_t)k * 256 + f8 * 8);
        float4 y = *(const float4*)(keys + (size_t)k * 256 + f8 * 8 + 4);
        f16x8 h = {(_Float16)x.x, (_Float16)x.y, (_Float16)x.z, (_Float16)x.w,
                   (_Float16)y.x, (_Float16)y.y, (_Float16)y.z, (_Float16)y.w};
        *(f16x8*)((char*)keysSW + ((size_t)(k >> 5) << 14) + swz2(k & 31, f8 * 16)) = h;
    } else if (b < 768) {               // Wq 256x256
        int i = (b - 512) * 256 + tid;
        int k = i >> 8, n = i & 255;
        int d = ((n >> 4) * 8 + (k >> 5)) * 512 + (((k >> 3) & 3) * 16 + (n & 15)) * 8 + (k & 7);
        Wq2[d] = (_Float16)Wq[i];
    } else if (b < 1280) {              // W1 512x256
        int i = (b - 768) * 256 + tid;
        int k = i >> 8, n = i & 255;
        int d = ((n >> 4) * 16 + (k >> 5)) * 512 + (((k >> 3) & 3) * 16 + (n & 15)) * 8 + (k & 7);
        W12[d] = (_Float16)W1[i];
    } else {                            // W2 256x256
        int i = (b - 1280) * 256 + tid;
        int k = i >> 8, n = i & 255;
        int d = ((n >> 4) * 8 + (k >> 5)) * 512 + (((k >> 3) & 3) * 16 + (n & 15)) * 8 + (k & 7);
        W22[d] = (_Float16)W2[i];
    }
}

// ---------------------------------------------------------------------------
// Packed selection key: [31:12] = ordered-uint fp32 score (truncated),
// [11:0] = ~idx (12 bits) -> bigger key = higher score, ties: lower idx wins.
// ---------------------------------------------------------------------------
__device__ __forceinline__ unsigned pack_key(float s, unsigned inv12) {
    unsigned u = __float_as_uint(s);
    unsigned m = (unsigned)(((int)u) >> 31) | 0x80000000u;
    unsigned k = u ^ m;
    return (k & 0xFFFFF000u) | inv12;
}

// v_med3_u32: single-instruction sorted-list insert step.
__device__ __forceinline__ unsigned med3u(unsigned a, unsigned b, unsigned c) {
    unsigned d;
    asm("v_med3_u32 %0, %1, %2, %3" : "=v"(d) : "v"(a), "v"(b), "v"(c));
    return d;
}

template <int N>
__device__ __forceinline__ void ins(unsigned* t, unsigned key) {
#pragma unroll
    for (int p = N - 1; p > 0; --p) t[p] = med3u(t[p - 1], t[p], key);
    t[0] = (t[0] > key) ? t[0] : key;
}

// async global -> LDS, 16 B per lane (wave-uniform LDS base + lane*16).
__device__ __forceinline__ void load_lds16(const void* g, void* l) {
    __builtin_amdgcn_global_load_lds(
        (const __attribute__((address_space(1))) unsigned int*)g,
        (__attribute__((address_space(3))) unsigned int*)l, 16, 0, 0);
}

// ---------------------------------------------------------------------------
// Fully fused: proj -> sim -> top8 -> softmax -> gather -> MLP1 -> MLP2.
// 64 rows / block, 4 waves. LDS = 36.9 KB time-shared (query -> qproj ->
// key double-buffer 2x16KB -> retrieved -> query -> h; +4 KB merge scratch)
// -> 3 blocks/CU. amdgpu_waves_per_eu(3,3) gives the allocator the true
// 170-VGPR budget so the ~160-reg sim state (af 64 + tk 48 + bf + accs)
// fits with NO scratch spills (rounds 2-4 silently spilled at a 128 cap).
// Sim: wave w owns A-row-group (w&1) (32 rows in regs) x key-half (w>>1)
// of each 32-key tile -> 8 ds_read_b128 : 16 MFMA. Tiles staged with
// global_load_lds from the pre-swizzled image, double-buffered.
// ---------------------------------------------------------------------------
__global__ __launch_bounds__(256) __attribute__((amdgpu_waves_per_eu(3, 3)))
void fused_all(
        const float*    __restrict__ query,   // BN x 256 fp32
        const _Float16* __restrict__ keysSW,  // 128 tiles x 16 KB (ws, pre-swizzled)
        const float*    __restrict__ vals,    // 4096 x 256 fp32
        const _Float16* __restrict__ Wq2,     // fragment-ordered (ws)
        const float*    __restrict__ bq,
        const _Float16* __restrict__ W12,     // fragment-ordered (ws)
        const float*    __restrict__ b1,
        const _Float16* __restrict__ W22,     // fragment-ordered (ws)
        const float*    __restrict__ b2,
        float* __restrict__ out)              // BN x 256 fp32
{
    __shared__ __attribute__((aligned(16))) unsigned char SM[36864];
    unsigned* const Mrg = (unsigned*)(SM + 32768);   // [2][64][8] u32 = 4 KB

    const int tid  = threadIdx.x;
    const int lane = tid & 63, quad = lane >> 4, l16 = lane & 15, wave = tid >> 6;
    const size_t row0 = (size_t)blockIdx.x * 64;

    // ---- P0: stage 64 query rows (fp32 -> f16, swizzled) into SM[0,32K) ----
#pragma unroll
    for (int j = 0; j < 8; ++j) {
        int u = (j << 8) + tid;
        int r = u >> 5, f = (u & 31) << 3;
        float4 x = *(const float4*)(query + (row0 + r) * 256 + f);
        float4 y = *(const float4*)(query + (row0 + r) * 256 + f + 4);
        f16x8 h = {(_Float16)x.x, (_Float16)x.y, (_Float16)x.z, (_Float16)x.w,
                   (_Float16)y.x, (_Float16)y.y, (_Float16)y.z, (_Float16)y.w};
        *(f16x8*)(SM + swz2(r, f << 1)) = h;
    }
    __syncthreads();

    // ---- P1: qproj = query @ Wq + bq -> SM (in place over query) ----
    {
        f32x4 acc[4][4];
#pragma unroll
        for (int rt = 0; rt < 4; ++rt)
#pragma unroll
            for (int nt = 0; nt < 4; ++nt)
                acc[rt][nt] = (f32x4){0.f, 0.f, 0.f, 0.f};
#pragma unroll
        for (int kf = 0; kf < 8; ++kf) {
            f16x8 a[4];
#pragma unroll
            for (int rt = 0; rt < 4; ++rt)
                a[rt] = *(const f16x8*)(SM + swz2(rt * 16 + l16, kf * 64 + quad * 16));
#pragma unroll
            for (int nt = 0; nt < 4; ++nt) {
                f16x8 b = *(const f16x8*)(Wq2 + (size_t)((wave + nt * 4) * 8 + kf) * 512 + lane * 8);
#pragma unroll
                for (int rt = 0; rt < 4; ++rt)
                    acc[rt][nt] = MFMA(a[rt], b, acc[rt][nt]);
            }
        }
        __syncthreads();   // all query reads done before in-place overwrite
#pragma unroll
        for (int nt = 0; nt < 4; ++nt) {
            int col = wave * 16 + nt * 64 + l16;
            float bv = bq[col];
#pragma unroll
            for (int rt = 0; rt < 4; ++rt)
#pragma unroll
                for (int r = 0; r < 4; ++r) {
                    int row = rt * 16 + quad * 4 + r;
                    *(_Float16*)(SM + swz2(row, col * 2)) =
                        (_Float16)(acc[rt][nt][r] + bv);
                }
        }
    }
    __syncthreads();

    // ---- af: this wave's 32 qproj rows (group wave&1) into registers ----
    f16x8 af0[8], af1[8];
    {
        const int ag = (wave & 1) * 32;
#pragma unroll
        for (int nk = 0; nk < 8; ++nk) {
            af0[nk] = *(const f16x8*)(SM + swz2(ag + l16,      nk * 64 + quad * 16));
            af1[nk] = *(const f16x8*)(SM + swz2(ag + 16 + l16, nk * 64 + quad * 16));
        }
    }
    __syncthreads();   // af reads drained before key staging overwrites

    // ---- stage key tile 0 into buf0 = SM[0,16K) ----
    {
        const char* src = (const char*)keysSW + wave * 4096;
#pragma unroll
        for (int j = 0; j < 4; ++j)
            load_lds16(src + j * 1024 + lane * 16, (char*)SM + wave * 4096 + j * 1024);
    }
    __syncthreads();

    // ---- P2: sim over 128 double-buffered 32-key tiles ----
    unsigned tk[8][6];   // 8 streams: rows quad*4+r of af0 / af1
#pragma unroll
    for (int s = 0; s < 8; ++s)
#pragma unroll
        for (int e = 0; e < 6; ++e) tk[s][e] = 0u;

    const int kl = (wave >> 1) * 16;     // this wave's key-half within a tile

#pragma unroll 1
    for (int t = 0; t < 128; ++t) {
        unsigned char* cur = SM + ((t & 1) << 14);
        unsigned char* nxt = SM + (((t + 1) & 1) << 14);
        // prefetch tile t+1 (async -> LDS; drained at this iter's barrier)
        {
            const char* src = (const char*)keysSW + ((size_t)((t + 1) & 127) << 14) + wave * 4096;
#pragma unroll
            for (int j = 0; j < 4; ++j)
                load_lds16(src + j * 1024 + lane * 16, (char*)nxt + wave * 4096 + j * 1024);
        }
        // compute this wave's key-half: 8 ds_read_b128 -> 16 MFMA
        f16x8 bf[8];
#pragma unroll
        for (int nk = 0; nk < 8; ++nk)
            bf[nk] = *(const f16x8*)(cur + swz2(kl + l16, nk * 64 + quad * 16));
        f32x4 a0 = {0.f, 0.f, 0.f, 0.f};
        f32x4 a1 = {0.f, 0.f, 0.f, 0.f};
#pragma unroll
        for (int nk = 0; nk < 8; ++nk) {
            a0 = MFMA(af0[nk], bf[nk], a0);
            a1 = MFMA(af1[nk], bf[nk], a1);
        }
        unsigned inv = (~(unsigned)((t << 5) + kl + l16)) & 0xFFFu;
#pragma unroll
        for (int r = 0; r < 4; ++r) ins<6>(tk[r],     pack_key(a0[r], inv));
#pragma unroll
        for (int r = 0; r < 4; ++r) ins<6>(tk[4 + r], pack_key(a1[r], inv));
        __syncthreads();
    }

    // ---- in-register butterfly (16 l16 lanes; wave saw its key-half) ----
    // Stage A (xor1): fold bank dim. depth 6 -> 7.
    unsigned m4[4][7];
    {
        const int kb = l16 & 1;
#pragma unroll
        for (int j = 0; j < 4; ++j) {
#pragma unroll
            for (int e = 0; e < 6; ++e) m4[j][e] = kb ? tk[4 + j][e] : tk[j][e];
            m4[j][6] = 0u;
#pragma unroll
            for (int e = 0; e < 6; ++e) {
                unsigned snd = kb ? tk[j][e] : tk[4 + j][e];
                ins<7>(m4[j], __shfl_xor(snd, 1));
            }
        }
    }
    // Stage B (xor2): fold row-pair. depth 7 -> 8.
    unsigned m2[2][8];
    {
        const int k2 = (l16 >> 1) & 1;
#pragma unroll
        for (int j = 0; j < 2; ++j) {
#pragma unroll
            for (int e = 0; e < 7; ++e) m2[j][e] = k2 ? m4[2 + j][e] : m4[j][e];
            m2[j][7] = 0u;
#pragma unroll
            for (int e = 0; e < 7; ++e) {
                unsigned snd = k2 ? m4[j][e] : m4[2 + j][e];
                ins<8>(m2[j], __shfl_xor(snd, 2));
            }
        }
    }
    // Stage C (xor4): fold row parity. depth 8.
    unsigned fm[8];
    {
        const int k3 = (l16 >> 2) & 1;
        unsigned oth[8];
#pragma unroll
        for (int e = 0; e < 8; ++e) {
            fm[e]  = k3 ? m2[1][e] : m2[0][e];
            oth[e] = k3 ? m2[0][e] : m2[1][e];
        }
#pragma unroll
        for (int e = 0; e < 8; ++e) ins<8>(fm, __shfl_xor(oth[e], 4));
    }
    // Stage D (xor8): merge key-slot halves (snapshot both sides).
    {
        unsigned rcv[8];
#pragma unroll
        for (int e = 0; e < 8; ++e) rcv[e] = __shfl_xor(fm[e], 8);
#pragma unroll
        for (int e = 0; e < 8; ++e) ins<8>(fm, rcv[e]);
    }
    // Dump per-(row, key-half) top-8: lanes l16<8 own distinct local rows.
    if (l16 < 8) {
        const int rl  = quad * 4 + 2 * ((l16 >> 1) & 1) + ((l16 >> 2) & 1) + 16 * (l16 & 1);
        const int row = (wave & 1) * 32 + rl;
#pragma unroll
        for (int e = 0; e < 8; ++e) Mrg[((wave >> 1) * 64 + row) * 8 + e] = fm[e];
    }
    __syncthreads();

    // ---- 2-way cross-half merge (quads duplicate -> broadcast reads) ----
    const int rmap = ((wave & 1) << 5) + ((wave & 2) << 3);  // w:0,1,2,3 -> 0,32,16,48
    int idx[8];
    {
        const int row = rmap + l16;
        unsigned f[8];
#pragma unroll
        for (int e = 0; e < 8; ++e) f[e] = Mrg[row * 8 + e];
#pragma unroll
        for (int e = 0; e < 8; ++e) ins<8>(f, Mrg[(64 + row) * 8 + e]);
#pragma unroll
        for (int e = 0; e < 8; ++e) idx[e] = 4095 - (int)(f[e] & 0xFFFu);
    }

    // ---- exact fp32 scores (qproj from af regs, keys from keysSW) + softmax ----
    float wt[8];
    {
        f16x8 afr[8];
        const bool hi = (wave & 2) != 0;   // row rmap+l16 sits in af1 if w&2
#pragma unroll
        for (int nk = 0; nk < 8; ++nk) afr[nk] = hi ? af1[nk] : af0[nk];
        float ps[8];
#pragma unroll
        for (int e = 0; e < 8; ++e) {
            const unsigned char* kb =
                (const unsigned char*)keysSW + ((size_t)(idx[e] >> 5) << 14);
            const int kr = idx[e] & 31;
            float s = 0.f;
#pragma unroll
            for (int nk = 0; nk < 8; ++nk) {
                f16x8 kv = *(const f16x8*)(kb + swz2(kr, nk * 64 + quad * 16));
                f16x8 qv = afr[nk];
#pragma unroll
                for (int i = 0; i < 8; ++i) s += (float)qv[i] * (float)kv[i];
            }
            ps[e] = s;
        }
#pragma unroll
        for (int e = 0; e < 8; ++e) {      // reduce k-slices across quads
            ps[e] += __shfl_xor(ps[e], 16);
            ps[e] += __shfl_xor(ps[e], 32);
        }
        float mx = ps[0];
#pragma unroll
        for (int e = 1; e < 8; ++e) mx = fmaxf(mx, ps[e]);
        float z = 0.f;
#pragma unroll
        for (int e = 0; e < 8; ++e) { wt[e] = __expf(ps[e] - mx); z += wt[e]; }
        float rz = 1.f / z;
#pragma unroll
        for (int e = 0; e < 8; ++e) wt[e] *= rz;
    }

    // ---- P3: weighted gather; lane = row rmap+l16, cols quad*64.. -> SM ----
    {
        float rv[64];
#pragma unroll
        for (int i = 0; i < 64; ++i) rv[i] = 0.f;
#pragma unroll
        for (int e = 0; e < 8; ++e) {
            const float4* vp = (const float4*)(vals + (size_t)(idx[e] & (MSZ - 1)) * 256 + quad * 64);
            float w = wt[e];
#pragma unroll
            for (int j = 0; j < 16; ++j) {
                float4 v = vp[j];
                rv[j * 4 + 0] += w * v.x; rv[j * 4 + 1] += w * v.y;
                rv[j * 4 + 2] += w * v.z; rv[j * 4 + 3] += w * v.w;
            }
        }
        const int row = rmap + l16;
#pragma unroll
        for (int j = 0; j < 8; ++j) {
            f16x8 h = {(_Float16)rv[j * 8 + 0], (_Float16)rv[j * 8 + 1],
                       (_Float16)rv[j * 8 + 2], (_Float16)rv[j * 8 + 3],
                       (_Float16)rv[j * 8 + 4], (_Float16)rv[j * 8 + 5],
                       (_Float16)rv[j * 8 + 6], (_Float16)rv[j * 8 + 7]};
            *(f16x8*)(SM + swz2(row, quad * 128 + (j << 4))) = h;
        }
    }
    __syncthreads();   // retrieved fully staged

    // ---- P4a: acc = retrieved @ W1[256:512] ----
    f32x4 acc[4][4];
#pragma unroll
    for (int rt = 0; rt < 4; ++rt)
#pragma unroll
        for (int nt = 0; nt < 4; ++nt)
            acc[rt][nt] = (f32x4){0.f, 0.f, 0.f, 0.f};
#pragma unroll
    for (int kf = 0; kf < 8; ++kf) {
        f16x8 a[4];
#pragma unroll
        for (int rt = 0; rt < 4; ++rt)
            a[rt] = *(const f16x8*)(SM + swz2(rt * 16 + l16, kf * 64 + quad * 16));
#pragma unroll
        for (int nt = 0; nt < 4; ++nt) {
            f16x8 b = *(const f16x8*)(W12 + (size_t)((wave + nt * 4) * 16 + 8 + kf) * 512 + lane * 8);
#pragma unroll
            for (int rt = 0; rt < 4; ++rt)
                acc[rt][nt] = MFMA(a[rt], b, acc[rt][nt]);
        }
    }
    __syncthreads();   // retrieved reads done before overwrite

    // ---- reload raw query (fp32 -> f16) into SM ----
#pragma unroll
    for (int j = 0; j < 8; ++j) {
        int u = (j << 8) + tid;
        int r = u >> 5, f = (u & 31) << 3;
        float4 x = *(const float4*)(query + (row0 + r) * 256 + f);
        float4 y = *(const float4*)(query + (row0 + r) * 256 + f + 4);
        f16x8 h = {(_Float16)x.x, (_Float16)x.y, (_Float16)x.z, (_Float16)x.w,
                   (_Float16)y.x, (_Float16)y.y, (_Float16)y.z, (_Float16)y.w};
        *(f16x8*)(SM + swz2(r, f << 1)) = h;
    }
    __syncthreads();

    // ---- P4b: acc += query @ W1[0:256]; h = relu(acc + b1) -> SM ----
    {
#pragma unroll
        for (int kf = 0; kf < 8; ++kf) {
            f16x8 a[4];
#pragma unroll
            for (int rt = 0; rt < 4; ++rt)
                a[rt] = *(const f16x8*)(SM + swz2(rt * 16 + l16, kf * 64 + quad * 16));
#pragma unroll
            for (int nt = 0; nt < 4; ++nt) {
                f16x8 b = *(const f16x8*)(W12 + (size_t)((wave + nt * 4) * 16 + kf) * 512 + lane * 8);
#pragma unroll
                for (int rt = 0; rt < 4; ++rt)
                    acc[rt][nt] = MFMA(a[rt], b, acc[rt][nt]);
            }
        }
        __syncthreads();   // query reads done before in-place overwrite with h
#pragma unroll
        for (int nt = 0; nt < 4; ++nt) {
            int col = wave * 16 + nt * 64 + l16;
            float bv = b1[col];
#pragma unroll
            for (int rt = 0; rt < 4; ++rt)
#pragma unroll
                for (int r = 0; r < 4; ++r) {
                    int row = rt * 16 + quad * 4 + r;
                    *(_Float16*)(SM + swz2(row, col * 2)) =
                        (_Float16)fmaxf(acc[rt][nt][r] + bv, 0.f);
                }
        }
    }
    __syncthreads();

    // ---- P5: out = h @ W2 + b2 -> global (fp32) ----
    {
        f32x4 acc2[4][4];
#pragma unroll
        for (int rt = 0; rt < 4; ++rt)
#pragma unroll
            for (int nt = 0; nt < 4; ++nt)
                acc2[rt][nt] = (f32x4){0.f, 0.f, 0.f, 0.f};
#pragma unroll
        for (int kf = 0; kf < 8; ++kf) {
            f16x8 a[4];
#pragma unroll
            for (int rt = 0; rt < 4; ++rt)
                a[rt] = *(const f16x8*)(SM + swz2(rt * 16 + l16, kf * 64 + quad * 16));
#pragma unroll
            for (int nt = 0; nt < 4; ++nt) {
                f16x8 b = *(const f16x8*)(W22 + (size_t)((wave + nt * 4) * 8 + kf) * 512 + lane * 8);
#pragma unroll
                for (int rt = 0; rt < 4; ++rt)
                    acc2[rt][nt] = MFMA(a[rt], b, acc2[rt][nt]);
            }
        }
#pragma unroll
        for (int nt = 0; nt < 4; ++nt) {
            int col = wave * 16 + nt * 64 + l16;
            float bv = b2[col];
#pragma unroll
            for (int rt = 0; rt < 4; ++rt)
#pragma unroll
                for (int r = 0; r < 4; ++r)
                    out[(row0 + rt * 16 + quad * 4 + r) * 256 + col] =
                        acc2[rt][nt][r] + bv;
        }
    }
}

// ---------------------------------------------------------------------------
extern "C" void kernel_launch(void* const* d_in, const int* in_sizes, int n_in,
                              void* d_out, int out_size, void* d_ws, size_t ws_size,
                              hipStream_t stream) {
    const float* query = (const float*)d_in[0];
    const float* keys  = (const float*)d_in[1];
    const float* vals  = (const float*)d_in[2];
    const float* Wq    = (const float*)d_in[3];
    const float* bq    = (const float*)d_in[4];
    const float* W1    = (const float*)d_in[5];
    const float* b1    = (const float*)d_in[6];
    const float* W2    = (const float*)d_in[7];
    const float* b2    = (const float*)d_in[8];
    float* out = (float*)d_out;

    // ws layout (f16): keysSW 2 MB | Wq2 128K | W12 256K | W22 128K = 2.5 MB
    char* ws = (char*)d_ws;
    _Float16* keysSW = (_Float16*)(ws);
    _Float16* Wq2    = (_Float16*)(ws + 2097152);
    _Float16* W12    = (_Float16*)(ws + 2097152 + 131072);
    _Float16* W22    = (_Float16*)(ws + 2097152 + 131072 + 262144);

    prep<<<1536, 256, 0, stream>>>(keys, keysSW, Wq, Wq2, W1, W12, W2, W22);

    fused_all<<<BN / 64, 256, 0, stream>>>(query, keysSW, vals, Wq2, bq,
                                           W12, b1, W22, b2, out);
}